// Round 5
// baseline (64.017 us; speedup 1.0000x reference)
//
#include <hip/hip_runtime.h>
#include <hip/hip_bf16.h>

typedef __attribute__((ext_vector_type(8))) short short8;
typedef __attribute__((ext_vector_type(4))) float floatx4;

#define L2EPS 1e-12f

__device__ __forceinline__ unsigned short f2bf(float f) {
  union { float f; unsigned u; } c; c.f = f;
  unsigned u = c.u;
  unsigned r = (u + 0x7fffu + ((u >> 16) & 1u)) >> 16;  // RNE
  return (unsigned short)r;
}

__device__ __forceinline__ void gload_lds16(const void* g, void* l) {
  __builtin_amdgcn_global_load_lds(
      (const __attribute__((address_space(1))) unsigned int*)g,
      (__attribute__((address_space(3))) unsigned int*)l,
      16, 0, 0);
}

// ---------------------------------------------------------------------------
// Kernel 1: per-row inverse L2 norm of W (D rows of length N). One block/row.
// ---------------------------------------------------------------------------
__global__ __launch_bounds__(256) void wnorm_kernel(const float* __restrict__ W,
                                                    float* __restrict__ rnw, int N) {
  const int d = blockIdx.x;
  const float2* row2 = (const float2*)(W + (size_t)d * N);
  const int n2 = N >> 1;
  float s = 0.f;
  for (int i = threadIdx.x; i < n2; i += 256) {
    const float2 v = row2[i];
    s += v.x * v.x + v.y * v.y;
  }
  if (threadIdx.x == 0 && (N & 1)) {
    const float v = W[(size_t)d * N + (N - 1)];
    s += v * v;
  }
#pragma unroll
  for (int off = 32; off > 0; off >>= 1) s += __shfl_xor(s, off);
  __shared__ float red[4];
  if ((threadIdx.x & 63) == 0) red[threadIdx.x >> 6] = s;
  __syncthreads();
  if (threadIdx.x == 0) {
    const float t = red[0] + red[1] + red[2] + red[3];
    rnw[d] = rsqrtf(fmaxf(t, L2EPS));
  }
}

// ---------------------------------------------------------------------------
// Kernel 2 (fused dispatch): blocks [0,nxb): normalize x rows AND fold rnw
// (A[b,d] = xn[b,d]*rnw[d], bf16). Blocks [nxb,...): transpose-cast
// BT[n][d] = bf16(W[d][n]), n zero-padded to Npad.
// ---------------------------------------------------------------------------
__global__ __launch_bounds__(256) void prep_kernel(const float* __restrict__ x,
                                                   const float* __restrict__ W,
                                                   const float* __restrict__ rnw,
                                                   unsigned short* __restrict__ xb,
                                                   unsigned short* __restrict__ BT,
                                                   int N, int nxb, int nwx) {
  const int bid = blockIdx.x;
  if (bid < nxb) {
    const int lane = threadIdx.x & 63;
    const int wave = threadIdx.x >> 6;
    const int row  = bid * 4 + wave;
    const float4* xr = (const float4*)(x + (size_t)row * 512);
    const float4 v0 = xr[lane * 2];
    const float4 v1 = xr[lane * 2 + 1];
    float s = v0.x*v0.x + v0.y*v0.y + v0.z*v0.z + v0.w*v0.w
            + v1.x*v1.x + v1.y*v1.y + v1.z*v1.z + v1.w*v1.w;
#pragma unroll
    for (int off = 32; off > 0; off >>= 1) s += __shfl_xor(s, off);
    const float r = rsqrtf(fmaxf(s, L2EPS));
    const float4 w0 = ((const float4*)rnw)[lane * 2];
    const float4 w1 = ((const float4*)rnw)[lane * 2 + 1];
    short8 o;
    o[0] = (short)f2bf(v0.x * r * w0.x); o[1] = (short)f2bf(v0.y * r * w0.y);
    o[2] = (short)f2bf(v0.z * r * w0.z); o[3] = (short)f2bf(v0.w * r * w0.w);
    o[4] = (short)f2bf(v1.x * r * w1.x); o[5] = (short)f2bf(v1.y * r * w1.y);
    o[6] = (short)f2bf(v1.z * r * w1.z); o[7] = (short)f2bf(v1.w * r * w1.w);
    *(short8*)(xb + (size_t)row * 512 + lane * 8) = o;
  } else {
    __shared__ unsigned short tile[32][33];
    const int wb = bid - nxb;
    const int n0 = (wb % nwx) * 32;
    const int d0 = (wb / nwx) * 32;
    const int tx = threadIdx.x & 31;
    const int ty = threadIdx.x >> 5;  // 0..7
#pragma unroll
    for (int i = 0; i < 4; ++i) {
      const int dl = ty + i * 8;
      const int n = n0 + tx;
      float v = 0.f;
      if (n < N) v = W[(size_t)(d0 + dl) * N + n];
      tile[tx][dl] = f2bf(v);
    }
    __syncthreads();
#pragma unroll
    for (int i = 0; i < 4; ++i) {
      const int nl = ty + i * 8;
      BT[(size_t)(n0 + nl) * 512 + d0 + tx] = tile[nl][tx];
    }
  }
}

// ---------------------------------------------------------------------------
// Kernel 3: GEMM. 256x256 tile, 8 waves (2M x 4N, wave out = 128x64),
// BK=32, 4-deep LDS pipeline (128KB, 1 block/CU), 3-ahead staging,
// counted vmcnt(8) (never drains in steady state), 1 barrier per K-tile,
// chunk-XOR swizzle both sides (0 conflicts, verified r3). K=512 -> 16 tiles.
// ---------------------------------------------------------------------------
#define NT 16

__global__ __launch_bounds__(512, 2) void gemm_kernel(
    const unsigned short* __restrict__ A,   // (4096,512) bf16 (xn * rnw)
    const unsigned short* __restrict__ BT,  // (6144,512) bf16 (W^T)
    float* __restrict__ C,                  // (4096,N) f32
    int N, int nbx, int nby) {
  __shared__ unsigned short As[4][256 * 32];
  __shared__ unsigned short Bs[4][256 * 32];

  const int tid = threadIdx.x;
  const int l   = tid & 63;
  const int w   = tid >> 6;   // 0..7
  const int wr  = w >> 2;     // 0..1
  const int wc  = w & 3;      // 0..3

  // XCD swizzle: grid = 384 = 8 * 48; column-major chunks (B-panel L2 reuse).
  const int grid = nbx * nby;
  const int bid  = blockIdx.x;
  int swz = bid;
  if ((grid & 7) == 0) swz = (bid & 7) * (grid >> 3) + (bid >> 3);
  const int bx = swz / nby;
  const int by = swz % nby;
  const int row0 = by * 256;
  const int col0 = bx * 256;

  floatx4 acc[8][4];
#pragma unroll
  for (int m = 0; m < 8; ++m)
#pragma unroll
    for (int n = 0; n < 4; ++n)
      acc[m][n] = (floatx4){0.f, 0.f, 0.f, 0.f};

  // staging: one instr = 512 thr x 16B = 8KB = 128 rows of 64B.
  // LDS dest linear; SOURCE chunk pre-swizzled: chunk_g = (tid&3) ^ ((row>>1)&3).
  const int srow = tid >> 2;                                  // 0..127
  const int sch  = ((tid & 3) ^ ((tid >> 3) & 3)) * 8;        // elems
  const unsigned short* Ag = A  + (size_t)(row0 + srow) * 512 + sch;
  const unsigned short* Bg = BT + (size_t)(col0 + srow) * 512 + sch;
  const int ldst = srow * 32 + (tid & 3) * 8;                 // elems

#define STAGE(t_) do { \
    gload_lds16(Ag + (t_) * 32,                     &As[(t_) & 3][ldst]); \
    gload_lds16(Ag + (size_t)128 * 512 + (t_) * 32, &As[(t_) & 3][ldst + 4096]); \
    gload_lds16(Bg + (t_) * 32,                     &Bs[(t_) & 3][ldst]); \
    gload_lds16(Bg + (size_t)128 * 512 + (t_) * 32, &Bs[(t_) & 3][ldst + 4096]); \
  } while (0)
#define CFENCE asm volatile("" ::: "memory")

  // frag-read geometry (swizzled chunk; rows base%16==0 so swz dep = ln15 only)
  const int ln15 = l & 15;
  const int qs   = (((l >> 4) ^ ((ln15 >> 1) & 3))) * 8;      // swizzled chunk
  const int ab   = (wr * 128 + ln15) * 32 + qs;               // + m*512
  const int bb   = (wc * 64 + ln15) * 32 + qs;                // + n*512

  // prologue: 3 tiles in flight (12 loads); wait tile0 (leave 8).
  STAGE(0); STAGE(1); STAGE(2);
  asm volatile("s_waitcnt vmcnt(8)" ::: "memory");
  __builtin_amdgcn_s_barrier();
  CFENCE;

#pragma unroll
  for (int t = 0; t < NT; ++t) {
    const int b = t & 3;
    if (t + 3 < NT) STAGE(t + 3);   // writes buf (t-1)&3: reads done at barrier t-1
    CFENCE;
    short8 af[8], bf[4];
#pragma unroll
    for (int n = 0; n < 4; ++n) bf[n] = *(const short8*)&Bs[b][bb + n * 512];
#pragma unroll
    for (int m = 0; m < 8; ++m) af[m] = *(const short8*)&As[b][ab + m * 512];
    CFENCE;
    __builtin_amdgcn_s_setprio(1);
#pragma unroll
    for (int m = 0; m < 8; ++m)
#pragma unroll
      for (int n = 0; n < 4; ++n)
        acc[m][n] = __builtin_amdgcn_mfma_f32_16x16x32_bf16(af[m], bf[n], acc[m][n], 0, 0, 0);
    __builtin_amdgcn_s_setprio(0);
    CFENCE;
    // publish tile t+1 (counted: never below 8 until the tail)
    if (t < NT - 3)       asm volatile("s_waitcnt vmcnt(8)" ::: "memory");
    else if (t == NT - 3) asm volatile("s_waitcnt vmcnt(4)" ::: "memory");
    else if (t == NT - 2) asm volatile("s_waitcnt vmcnt(0)" ::: "memory");
    if (t < NT - 1) {
      __builtin_amdgcn_s_barrier();
      CFENCE;
    }
  }

  // epilogue: C/D layout col=lane&15, row=(lane>>4)*4+r; n-inner
  const int rb = row0 + wr * 128 + (l >> 4) * 4;
  const int cb = col0 + wc * 64 + ln15;
#pragma unroll
  for (int m = 0; m < 8; ++m) {
#pragma unroll
    for (int r = 0; r < 4; ++r) {
      const size_t o = (size_t)(rb + m * 16 + r) * N + cb;
#pragma unroll
      for (int n = 0; n < 4; ++n) {
        if (cb + n * 16 < N) C[o + n * 16] = acc[m][n][r];
      }
    }
  }
#undef STAGE
#undef CFENCE
}

// ---------------------------------------------------------------------------
extern "C" void kernel_launch(void* const* d_in, const int* in_sizes, int n_in,
                              void* d_out, int out_size, void* d_ws, size_t ws_size,
                              hipStream_t stream) {
  const float* x = (const float*)d_in[0];
  const float* W = (const float*)d_in[1];
  float* out = (float*)d_out;

  const int D = 512;
  const int B = in_sizes[0] / D;            // 4096
  const int N = in_sizes[1] / D;            // 5994
  const int Npad = ((N + 255) / 256) * 256; // 6144

  char* ws = (char*)d_ws;
  unsigned short* xb  = (unsigned short*)ws;                          // B*D*2
  unsigned short* BTb = (unsigned short*)(ws + (size_t)B * D * 2);    // Npad*D*2
  float* rnw = (float*)(ws + (size_t)B * D * 2 + (size_t)Npad * D * 2);

  const int nby = B / 256;         // 16
  const int nbx = Npad / 256;      // 24
  const int nxb = B / 4;           // 1024 xnorm blocks
  const int nwx = Npad / 32;       // 192 wtrans tiles per d-stripe
  const int nwb = nwx * (D / 32);  // 3072 wtrans blocks

  wnorm_kernel<<<D, 256, 0, stream>>>(W, rnw, N);
  prep_kernel<<<nxb + nwb, 256, 0, stream>>>(x, W, rnw, xb, BTb, N, nxb, nwx);
  gemm_kernel<<<nbx * nby, 512, 0, stream>>>(xb, BTb, out, N, nbx, nby);
}

// Round 6
// 61.381 us; speedup vs baseline: 1.0429x; 1.0429x over previous
//
#include <hip/hip_runtime.h>
#include <hip/hip_bf16.h>

typedef __attribute__((ext_vector_type(8))) short short8;
typedef __attribute__((ext_vector_type(4))) float floatx4;

#define L2EPS 1e-12f

__device__ __forceinline__ unsigned short f2bf(float f) {
  union { float f; unsigned u; } c; c.f = f;
  unsigned u = c.u;
  unsigned r = (u + 0x7fffu + ((u >> 16) & 1u)) >> 16;  // RNE
  return (unsigned short)r;
}

__device__ __forceinline__ void gload_lds16(const void* g, void* l) {
  __builtin_amdgcn_global_load_lds(
      (const __attribute__((address_space(1))) unsigned int*)g,
      (__attribute__((address_space(3))) unsigned int*)l,
      16, 0, 0);
}

// ---------------------------------------------------------------------------
// Kernel 1: per-row inverse L2 norm of W (D rows of length N). One block/row.
// ---------------------------------------------------------------------------
__global__ __launch_bounds__(256) void wnorm_kernel(const float* __restrict__ W,
                                                    float* __restrict__ rnw, int N) {
  const int d = blockIdx.x;
  const float2* row2 = (const float2*)(W + (size_t)d * N);
  const int n2 = N >> 1;
  float s = 0.f;
  for (int i = threadIdx.x; i < n2; i += 256) {
    const float2 v = row2[i];
    s += v.x * v.x + v.y * v.y;
  }
  if (threadIdx.x == 0 && (N & 1)) {
    const float v = W[(size_t)d * N + (N - 1)];
    s += v * v;
  }
#pragma unroll
  for (int off = 32; off > 0; off >>= 1) s += __shfl_xor(s, off);
  __shared__ float red[4];
  if ((threadIdx.x & 63) == 0) red[threadIdx.x >> 6] = s;
  __syncthreads();
  if (threadIdx.x == 0) {
    const float t = red[0] + red[1] + red[2] + red[3];
    rnw[d] = rsqrtf(fmaxf(t, L2EPS));
  }
}

// ---------------------------------------------------------------------------
// Kernel 2 (fused dispatch): blocks [0,nxb): normalize x rows AND fold rnw.
// Blocks [nxb,...): transpose-cast BT[n][d] = bf16(W[d][n]), zero-padded.
// ---------------------------------------------------------------------------
__global__ __launch_bounds__(256) void prep_kernel(const float* __restrict__ x,
                                                   const float* __restrict__ W,
                                                   const float* __restrict__ rnw,
                                                   unsigned short* __restrict__ xb,
                                                   unsigned short* __restrict__ BT,
                                                   int N, int nxb, int nwx) {
  const int bid = blockIdx.x;
  if (bid < nxb) {
    const int lane = threadIdx.x & 63;
    const int wave = threadIdx.x >> 6;
    const int row  = bid * 4 + wave;
    const float4* xr = (const float4*)(x + (size_t)row * 512);
    const float4 v0 = xr[lane * 2];
    const float4 v1 = xr[lane * 2 + 1];
    float s = v0.x*v0.x + v0.y*v0.y + v0.z*v0.z + v0.w*v0.w
            + v1.x*v1.x + v1.y*v1.y + v1.z*v1.z + v1.w*v1.w;
#pragma unroll
    for (int off = 32; off > 0; off >>= 1) s += __shfl_xor(s, off);
    const float r = rsqrtf(fmaxf(s, L2EPS));
    const float4 w0 = ((const float4*)rnw)[lane * 2];
    const float4 w1 = ((const float4*)rnw)[lane * 2 + 1];
    short8 o;
    o[0] = (short)f2bf(v0.x * r * w0.x); o[1] = (short)f2bf(v0.y * r * w0.y);
    o[2] = (short)f2bf(v0.z * r * w0.z); o[3] = (short)f2bf(v0.w * r * w0.w);
    o[4] = (short)f2bf(v1.x * r * w1.x); o[5] = (short)f2bf(v1.y * r * w1.y);
    o[6] = (short)f2bf(v1.z * r * w1.z); o[7] = (short)f2bf(v1.w * r * w1.w);
    *(short8*)(xb + (size_t)row * 512 + lane * 8) = o;
  } else {
    __shared__ unsigned short tile[32][33];
    const int wb = bid - nxb;
    const int n0 = (wb % nwx) * 32;
    const int d0 = (wb / nwx) * 32;
    const int tx = threadIdx.x & 31;
    const int ty = threadIdx.x >> 5;  // 0..7
#pragma unroll
    for (int i = 0; i < 4; ++i) {
      const int dl = ty + i * 8;
      const int n = n0 + tx;
      float v = 0.f;
      if (n < N) v = W[(size_t)(d0 + dl) * N + n];
      tile[tx][dl] = f2bf(v);
    }
    __syncthreads();
#pragma unroll
    for (int i = 0; i < 4; ++i) {
      const int nl = ty + i * 8;
      BT[(size_t)(n0 + nl) * 512 + d0 + tx] = tile[nl][tx];
    }
  }
}

// ---------------------------------------------------------------------------
// Kernel 3: GEMM, m201-style 8-phase schedule. 256x256 tile, BK=64, 8 waves
// (2M x 4N, wave=128x64). LDS: 2 dbuf x (A 256x64 + B 256x64) bf16 = 128KB.
// K=512 -> 8 K-tiles -> 4 iters x 8 phases. Per phase: {ds_reads | stage} ->
// [vmcnt(4) @ p3/p7] -> barrier -> 16 MFMA (setprio). Chunk-XOR swizzle
// chunk^ = chunk ^ (row&7): uniform 8 lanes/bank-group (0 conflicts).
// Stage plan (all write-after-read gaps >= 2 phases; hand-verified):
//   p1: A(2i+1)h0  p2: A(2i+1)h1 + B(2i+2)h0  p3: B(2i+2)h1
//   p5: A(2i+2)h0  p6: A(2i+2)h1              p7: B(2i+3)h0+h1
// ---------------------------------------------------------------------------
__global__ __launch_bounds__(512, 2) void gemm_kernel(
    const unsigned short* __restrict__ A,   // (4096,512) bf16 (xn * rnw)
    const unsigned short* __restrict__ BT,  // (6144,512) bf16 (W^T)
    float* __restrict__ C,                  // (4096,N) f32
    int N, int nbx, int nby) {
  __shared__ unsigned short As[2][256 * 64];
  __shared__ unsigned short Bs[2][256 * 64];

  const int tid = threadIdx.x;
  const int l   = tid & 63;
  const int w   = tid >> 6;   // 0..7
  const int wr  = w >> 2;     // 0..1
  const int wc  = w & 3;      // 0..3

  // XCD swizzle: grid = 384 = 8 * 48; column-major chunks (B-panel L2 reuse).
  const int grid = nbx * nby;
  const int bid  = blockIdx.x;
  int swz = bid;
  if ((grid & 7) == 0) swz = (bid & 7) * (grid >> 3) + (bid >> 3);
  const int bx = swz / nby;
  const int by = swz % nby;
  const int row0 = by * 256;
  const int col0 = bx * 256;

  floatx4 acc[8][4];
#pragma unroll
  for (int m = 0; m < 8; ++m)
#pragma unroll
    for (int n = 0; n < 4; ++n)
      acc[m][n] = (floatx4){0.f, 0.f, 0.f, 0.f};

  // staging: one instr = 512 thr x 16B = 8KB = 64 rows of 128B.
  // LDS dest linear (tid*16B); SOURCE chunk pre-swizzled: cg = (t&7)^((t>>3)&7).
  const int srow = tid >> 3;                               // 0..63
  const int sch  = ((tid & 7) ^ (srow & 7)) * 8;           // elems
  const unsigned short* Ap = A  + (size_t)(row0 + srow) * 512 + sch;
  const unsigned short* Bp = BT + (size_t)(col0 + srow) * 512 + sch;
  const int lo = tid * 8;                                  // LDS elems (tid*16B)

#define STG_A(s_, h_, kt_) do { \
    gload_lds16(Ap + (size_t)((h_) * 128) * 512 + (kt_) * 64,      &As[s_][((h_) * 128) * 64 + lo]); \
    gload_lds16(Ap + (size_t)((h_) * 128 + 64) * 512 + (kt_) * 64, &As[s_][((h_) * 128 + 64) * 64 + lo]); \
  } while (0)
#define STG_B(s_, h_, kt_) do { \
    gload_lds16(Bp + (size_t)((h_) * 128) * 512 + (kt_) * 64,      &Bs[s_][((h_) * 128) * 64 + lo]); \
    gload_lds16(Bp + (size_t)((h_) * 128 + 64) * 512 + (kt_) * 64, &Bs[s_][((h_) * 128 + 64) * 64 + lo]); \
  } while (0)
#define CFENCE asm volatile("" ::: "memory")

  // frag-read geometry: elem = row*64 + ((ks*4 + q) ^ (row&7))*8, row&7 = ln15&7
  const int ln15 = l & 15;
  const int q4   = l >> 4;                 // 0..3
  const int e7   = ln15 & 7;
  const int cs0  = ((q4) ^ e7) * 8;        // ks=0 swizzled chunk (elems)
  const int cs1  = ((4 + q4) ^ e7) * 8;    // ks=1
  const int abase = (wr * 128 + ln15) * 64;   // + m*1024
  const int bbase = (wc * 64 + ln15) * 64;    // + n*1024

  // prologue: A(0), B(0), B(1) (12 loads); wait A(0),B(0) (leave B(1)).
  STG_A(0, 0, 0); STG_A(0, 1, 0);
  STG_B(0, 0, 0); STG_B(0, 1, 0);
  STG_B(1, 0, 1); STG_B(1, 1, 1);
  asm volatile("s_waitcnt vmcnt(4)" ::: "memory");
  __builtin_amdgcn_s_barrier();
  CFENCE;

#pragma unroll
  for (int it = 0; it < 4; ++it) {
#pragma unroll
    for (int tt = 0; tt < 2; ++tt) {
      short8 bf[4][2];
      short8 af[2][2];
#pragma unroll
      for (int mp = 0; mp < 4; ++mp) {
        // ---- ds reads (B once per tile at mp0; A per phase) ----
        if (mp == 0) {
#pragma unroll
          for (int n = 0; n < 4; ++n) {
            bf[n][0] = *(const short8*)&Bs[tt][bbase + n * 1024 + cs0];
            bf[n][1] = *(const short8*)&Bs[tt][bbase + n * 1024 + cs1];
          }
        }
        af[0][0] = *(const short8*)&As[tt][abase + (2 * mp) * 1024 + cs0];
        af[0][1] = *(const short8*)&As[tt][abase + (2 * mp) * 1024 + cs1];
        af[1][0] = *(const short8*)&As[tt][abase + (2 * mp + 1) * 1024 + cs0];
        af[1][1] = *(const short8*)&As[tt][abase + (2 * mp + 1) * 1024 + cs1];
        // ---- stage (A-loads issued before B-loads within a phase: FIFO) ----
        if (tt == 0) {
          if (mp == 1)           STG_A(1, 0, 2 * it + 1);
          if (mp == 2) {         STG_A(1, 1, 2 * it + 1);
            if (it < 3)          STG_B(0, 0, 2 * it + 2); }
          if (mp == 3 && it < 3) STG_B(0, 1, 2 * it + 2);
        } else {
          if (mp == 1 && it < 3) STG_A(0, 0, 2 * it + 2);
          if (mp == 2 && it < 3) STG_A(0, 1, 2 * it + 2);
          if (mp == 3 && it < 3) { STG_B(1, 0, 2 * it + 3); STG_B(1, 1, 2 * it + 3); }
        }
        CFENCE;
        // ---- counted vmcnt at p3 / p7 only ----
        if (mp == 3 && tt == 0) {
          if (it < 3) asm volatile("s_waitcnt vmcnt(4)" ::: "memory");
          else        asm volatile("s_waitcnt vmcnt(0)" ::: "memory");
        }
        if (mp == 3 && tt == 1 && it < 3)
          asm volatile("s_waitcnt vmcnt(4)" ::: "memory");
        // ---- barrier (skipped in final 4 phases: read-only tail) ----
        if (!(it == 3 && tt == 1)) {
          __builtin_amdgcn_s_barrier();
          CFENCE;
        }
        // ---- 16 MFMA: quadrant m = {2mp, 2mp+1} x n x ks ----
        __builtin_amdgcn_s_setprio(1);
#pragma unroll
        for (int j = 0; j < 2; ++j)
#pragma unroll
          for (int n = 0; n < 4; ++n) {
            acc[2 * mp + j][n] = __builtin_amdgcn_mfma_f32_16x16x32_bf16(
                af[j][0], bf[n][0], acc[2 * mp + j][n], 0, 0, 0);
            acc[2 * mp + j][n] = __builtin_amdgcn_mfma_f32_16x16x32_bf16(
                af[j][1], bf[n][1], acc[2 * mp + j][n], 0, 0, 0);
          }
        __builtin_amdgcn_s_setprio(0);
        CFENCE;
      }
    }
  }

  // epilogue: C/D layout col=lane&15, row=(lane>>4)*4+r; n-inner
  const int rb = row0 + wr * 128 + (l >> 4) * 4;
  const int cb = col0 + wc * 64 + ln15;
#pragma unroll
  for (int m = 0; m < 8; ++m) {
#pragma unroll
    for (int r = 0; r < 4; ++r) {
      const size_t o = (size_t)(rb + m * 16 + r) * N + cb;
#pragma unroll
      for (int n = 0; n < 4; ++n) {
        if (cb + n * 16 < N) C[o + n * 16] = acc[m][n][r];
      }
    }
  }
#undef STG_A
#undef STG_B
#undef CFENCE
}

// ---------------------------------------------------------------------------
extern "C" void kernel_launch(void* const* d_in, const int* in_sizes, int n_in,
                              void* d_out, int out_size, void* d_ws, size_t ws_size,
                              hipStream_t stream) {
  const float* x = (const float*)d_in[0];
  const float* W = (const float*)d_in[1];
  float* out = (float*)d_out;

  const int D = 512;
  const int B = in_sizes[0] / D;            // 4096
  const int N = in_sizes[1] / D;            // 5994
  const int Npad = ((N + 255) / 256) * 256; // 6144

  char* ws = (char*)d_ws;
  unsigned short* xb  = (unsigned short*)ws;                          // B*D*2
  unsigned short* BTb = (unsigned short*)(ws + (size_t)B * D * 2);    // Npad*D*2
  float* rnw = (float*)(ws + (size_t)B * D * 2 + (size_t)Npad * D * 2);

  const int nby = B / 256;         // 16
  const int nbx = Npad / 256;      // 24
  const int nxb = B / 4;           // 1024 xnorm blocks
  const int nwx = Npad / 32;       // 192 wtrans tiles per d-stripe
  const int nwb = nwx * (D / 32);  // 3072 wtrans blocks

  wnorm_kernel<<<D, 256, 0, stream>>>(W, rnw, N);
  prep_kernel<<<nxb + nwb, 256, 0, stream>>>(x, W, rnw, xb, BTb, N, nxb, nwx);
  gemm_kernel<<<nbx * nby, 512, 0, stream>>>(xb, BTb, out, N, nbx, nby);
}

// Round 7
// 60.439 us; speedup vs baseline: 1.0592x; 1.0156x over previous
//
#include <hip/hip_runtime.h>
#include <hip/hip_bf16.h>

typedef __attribute__((ext_vector_type(8))) short short8;
typedef __attribute__((ext_vector_type(4))) float floatx4;

#define L2EPS 1e-12f

__device__ __forceinline__ unsigned short f2bf(float f) {
  union { float f; unsigned u; } c; c.f = f;
  unsigned u = c.u;
  unsigned r = (u + 0x7fffu + ((u >> 16) & 1u)) >> 16;  // RNE
  return (unsigned short)r;
}

__device__ __forceinline__ void gload_lds16(const void* g, void* l) {
  __builtin_amdgcn_global_load_lds(
      (const __attribute__((address_space(1))) unsigned int*)g,
      (__attribute__((address_space(3))) unsigned int*)l,
      16, 0, 0);
}

// ---------------------------------------------------------------------------
// Kernel 1: per-row inverse L2 norm of W (D rows of length N). One block/row.
// ---------------------------------------------------------------------------
__global__ __launch_bounds__(256) void wnorm_kernel(const float* __restrict__ W,
                                                    float* __restrict__ rnw, int N) {
  const int d = blockIdx.x;
  const float2* row2 = (const float2*)(W + (size_t)d * N);
  const int n2 = N >> 1;
  float s = 0.f;
  for (int i = threadIdx.x; i < n2; i += 256) {
    const float2 v = row2[i];
    s += v.x * v.x + v.y * v.y;
  }
  if (threadIdx.x == 0 && (N & 1)) {
    const float v = W[(size_t)d * N + (N - 1)];
    s += v * v;
  }
#pragma unroll
  for (int off = 32; off > 0; off >>= 1) s += __shfl_xor(s, off);
  __shared__ float red[4];
  if ((threadIdx.x & 63) == 0) red[threadIdx.x >> 6] = s;
  __syncthreads();
  if (threadIdx.x == 0) {
    const float t = red[0] + red[1] + red[2] + red[3];
    rnw[d] = rsqrtf(fmaxf(t, L2EPS));
  }
}

// ---------------------------------------------------------------------------
// Kernel 2 (fused dispatch): blocks [0,nxb): normalize x rows AND fold rnw.
// Blocks [nxb,...): transpose-cast BT[n][d] = bf16(W[d][n]), zero-padded.
// ---------------------------------------------------------------------------
__global__ __launch_bounds__(256) void prep_kernel(const float* __restrict__ x,
                                                   const float* __restrict__ W,
                                                   const float* __restrict__ rnw,
                                                   unsigned short* __restrict__ xb,
                                                   unsigned short* __restrict__ BT,
                                                   int N, int nxb, int nwx) {
  const int bid = blockIdx.x;
  if (bid < nxb) {
    const int lane = threadIdx.x & 63;
    const int wave = threadIdx.x >> 6;
    const int row  = bid * 4 + wave;
    const float4* xr = (const float4*)(x + (size_t)row * 512);
    const float4 v0 = xr[lane * 2];
    const float4 v1 = xr[lane * 2 + 1];
    float s = v0.x*v0.x + v0.y*v0.y + v0.z*v0.z + v0.w*v0.w
            + v1.x*v1.x + v1.y*v1.y + v1.z*v1.z + v1.w*v1.w;
#pragma unroll
    for (int off = 32; off > 0; off >>= 1) s += __shfl_xor(s, off);
    const float r = rsqrtf(fmaxf(s, L2EPS));
    const float4 w0 = ((const float4*)rnw)[lane * 2];
    const float4 w1 = ((const float4*)rnw)[lane * 2 + 1];
    short8 o;
    o[0] = (short)f2bf(v0.x * r * w0.x); o[1] = (short)f2bf(v0.y * r * w0.y);
    o[2] = (short)f2bf(v0.z * r * w0.z); o[3] = (short)f2bf(v0.w * r * w0.w);
    o[4] = (short)f2bf(v1.x * r * w1.x); o[5] = (short)f2bf(v1.y * r * w1.y);
    o[6] = (short)f2bf(v1.z * r * w1.z); o[7] = (short)f2bf(v1.w * r * w1.w);
    *(short8*)(xb + (size_t)row * 512 + lane * 8) = o;
  } else {
    __shared__ unsigned short tile[32][33];
    const int wb = bid - nxb;
    const int n0 = (wb % nwx) * 32;
    const int d0 = (wb / nwx) * 32;
    const int tx = threadIdx.x & 31;
    const int ty = threadIdx.x >> 5;  // 0..7
#pragma unroll
    for (int i = 0; i < 4; ++i) {
      const int dl = ty + i * 8;
      const int n = n0 + tx;
      float v = 0.f;
      if (n < N) v = W[(size_t)(d0 + dl) * N + n];
      tile[tx][dl] = f2bf(v);
    }
    __syncthreads();
#pragma unroll
    for (int i = 0; i < 4; ++i) {
      const int nl = ty + i * 8;
      BT[(size_t)(n0 + nl) * 512 + d0 + tx] = tile[nl][tx];
    }
  }
}

// ---------------------------------------------------------------------------
// Kernel 3: GEMM. Tile 128x384, BK=64, 8 waves (2M x 4N, wave 64x96 via
// j-interleaved cols: frag j at col wc*16 + j*64 -> np-phase B reads align
// with 128-row staged halves). LDS 2dbuf x (A 16KB + B 48KB) = 128KB.
// K=512 -> 8 K-tiles -> 4 iters x 6 phases. Uniform s_waitcnt vmcnt(6)
// (FIFO-ledger verified; B slack 3 phases, A slack 4-5). Grid 512 = exactly
// 2 passes of 256 CUs. Chunk-XOR swizzle both sides (0 conflicts, r3-proven).
// ---------------------------------------------------------------------------
__global__ __launch_bounds__(512, 2) void gemm_kernel(
    const unsigned short* __restrict__ A,   // (4096,512) bf16 (xn * rnw)
    const unsigned short* __restrict__ BT,  // (6144,512) bf16 (W^T)
    float* __restrict__ C,                  // (4096,N) f32
    int N) {
  __shared__ unsigned short As[2][128 * 64];
  __shared__ unsigned short Bs[2][384 * 64];

  const int tid = threadIdx.x;
  const int l   = tid & 63;
  const int w   = tid >> 6;   // 0..7
  const int wr  = w >> 2;     // 0..1
  const int wc  = w & 3;      // 0..3

  // XCD swizzle: 512 blocks = 8 XCD x 64; column-major chunks: each XCD owns
  // 2 B-panels (pass1: panel 2c, pass2: 2c+1), 384KB each -> L2-resident.
  const int bid = blockIdx.x;
  const int swz = (bid & 7) * 64 + (bid >> 3);
  const int by = swz & 31;   // 0..31
  const int bx = swz >> 5;   // 0..15
  const int row0 = by * 128;
  const int col0 = bx * 384;

  floatx4 acc[4][6];
#pragma unroll
  for (int m = 0; m < 4; ++m)
#pragma unroll
    for (int j = 0; j < 6; ++j)
      acc[m][j] = (floatx4){0.f, 0.f, 0.f, 0.f};

  // staging: one instr = 512 thr x 16B = 8KB = 64 rows of 128B.
  // LDS dest linear (tid*16B); SOURCE chunk pre-swizzled: cg = (tid&7)^(srow&7).
  const int srow = tid >> 3;                               // 0..63
  const int sch  = ((tid & 7) ^ (srow & 7)) * 8;           // elems
  const unsigned short* Ap = A  + (size_t)(row0 + srow) * 512 + sch;
  const unsigned short* Bp = BT + (size_t)(col0 + srow) * 512 + sch;
  const int lo = tid * 8;                                  // LDS elems

#define STG_A(s_, h_, t_) \
    gload_lds16(Ap + (size_t)((h_) * 64) * 512 + (t_) * 64, &As[s_][(h_) * 4096 + lo])
#define STG_B(s_, x_, t_) \
    gload_lds16(Bp + (size_t)((x_) * 64) * 512 + (t_) * 64, &Bs[s_][(x_) * 4096 + lo])
#define CFENCE asm volatile("" ::: "memory")

  // frag-read geometry: addr = row*64 + ((ks*4+q4)^(row&7))*8, row&7 = ln15&7
  const int ln15 = l & 15;
  const int q4   = l >> 4;
  const int e7   = ln15 & 7;
  const int cs0  = ((q4) ^ e7) * 8;
  const int cs1  = ((4 + q4) ^ e7) * 8;
  const int aoff = (wr * 64 + ln15) * 64;   // + m*1024
  const int boff = (wc * 16 + ln15) * 64;   // + j*4096

  // prologue: A0(h0,h1), B0(s0..s5), A1(h0,h1) = 10 loads; vmcnt(6) -> A0+B0s0,s1 landed.
  STG_A(0, 0, 0); STG_A(0, 1, 0);
  STG_B(0, 0, 0); STG_B(0, 1, 0); STG_B(0, 2, 0);
  STG_B(0, 3, 0); STG_B(0, 4, 0); STG_B(0, 5, 0);
  STG_A(1, 0, 1); STG_A(1, 1, 1);
  asm volatile("s_waitcnt vmcnt(6)" ::: "memory");
  __builtin_amdgcn_s_barrier();
  CFENCE;

  short8 af[4][2];
#pragma unroll
  for (int it = 0; it < 4; ++it) {
#pragma unroll
    for (int tt = 0; tt < 2; ++tt) {
#pragma unroll
      for (int np = 0; np < 3; ++np) {
        short8 bf[2][2];
        // ---- ds reads: af (all m) at np0; bf for j = 2np, 2np+1 ----
        if (np == 0) {
#pragma unroll
          for (int m = 0; m < 4; ++m) {
            af[m][0] = *(const short8*)&As[tt][aoff + m * 1024 + cs0];
            af[m][1] = *(const short8*)&As[tt][aoff + m * 1024 + cs1];
          }
        }
        bf[0][0] = *(const short8*)&Bs[tt][boff + (2 * np) * 4096 + cs0];
        bf[0][1] = *(const short8*)&Bs[tt][boff + (2 * np) * 4096 + cs1];
        bf[1][0] = *(const short8*)&Bs[tt][boff + (2 * np + 1) * 4096 + cs0];
        bf[1][1] = *(const short8*)&Bs[tt][boff + (2 * np + 1) * 4096 + cs1];
        // ---- stage plan (B sixths first, then A half; FIFO order matters) ----
        if (tt == 0) {
          const int t1 = 2 * it + 1;
          if (np == 0) { STG_B(1, 0, t1); STG_B(1, 1, t1); }
          if (np == 1) { STG_B(1, 2, t1); STG_B(1, 3, t1); if (it < 3) STG_A(0, 0, 2 * it + 2); }
          if (np == 2) { STG_B(1, 4, t1); STG_B(1, 5, t1); if (it < 3) STG_A(0, 1, 2 * it + 2); }
        } else if (it < 3) {
          const int t2 = 2 * it + 2;
          if (np == 0) { STG_B(0, 0, t2); STG_B(0, 1, t2); }
          if (np == 1) { STG_B(0, 2, t2); STG_B(0, 3, t2); STG_A(1, 0, 2 * it + 3); }
          if (np == 2) { STG_B(0, 4, t2); STG_B(0, 5, t2); STG_A(1, 1, 2 * it + 3); }
        }
        CFENCE;
        // ---- counted wait for next phase's reads (FIFO-ledger derived) ----
        if (it < 3) {
          asm volatile("s_waitcnt vmcnt(6)" ::: "memory");
        } else {
          if (tt == 0) {
            if (np == 0)      asm volatile("s_waitcnt vmcnt(6)" ::: "memory");
            else if (np == 1) asm volatile("s_waitcnt vmcnt(5)" ::: "memory");
            else              asm volatile("s_waitcnt vmcnt(4)" ::: "memory");
          } else {
            if (np == 0)      asm volatile("s_waitcnt vmcnt(2)" ::: "memory");
            else if (np == 1) asm volatile("s_waitcnt vmcnt(0)" ::: "memory");
            // (tt1,np2): nothing outstanding
          }
        }
        __builtin_amdgcn_s_barrier();
        CFENCE;
        // ---- 16 MFMA: m 0..3 x jj 0..1 x ks 0..1 ----
        __builtin_amdgcn_s_setprio(1);
#pragma unroll
        for (int m = 0; m < 4; ++m)
#pragma unroll
          for (int jj = 0; jj < 2; ++jj) {
            acc[m][2 * np + jj] = __builtin_amdgcn_mfma_f32_16x16x32_bf16(
                af[m][0], bf[jj][0], acc[m][2 * np + jj], 0, 0, 0);
            acc[m][2 * np + jj] = __builtin_amdgcn_mfma_f32_16x16x32_bf16(
                af[m][1], bf[jj][1], acc[m][2 * np + jj], 0, 0, 0);
          }
        __builtin_amdgcn_s_setprio(0);
        CFENCE;
      }
    }
  }

  // epilogue: C/D layout col=lane&15, row=(lane>>4)*4+r; j-inner (64-apart cols)
  const int rb = row0 + wr * 64 + q4 * 4;
  const int cb = col0 + wc * 16 + ln15;
#pragma unroll
  for (int m = 0; m < 4; ++m) {
#pragma unroll
    for (int r = 0; r < 4; ++r) {
      const size_t o = (size_t)(rb + m * 16 + r) * N + cb;
#pragma unroll
      for (int j = 0; j < 6; ++j) {
        if (cb + j * 64 < N) C[o + j * 64] = acc[m][j][r];
      }
    }
  }
#undef STG_A
#undef STG_B
#undef CFENCE
}

// ---------------------------------------------------------------------------
extern "C" void kernel_launch(void* const* d_in, const int* in_sizes, int n_in,
                              void* d_out, int out_size, void* d_ws, size_t ws_size,
                              hipStream_t stream) {
  const float* x = (const float*)d_in[0];
  const float* W = (const float*)d_in[1];
  float* out = (float*)d_out;

  const int D = 512;
  const int B = in_sizes[0] / D;            // 4096
  const int N = in_sizes[1] / D;            // 5994
  const int Npad = 6144;                    // 16 x 384

  char* ws = (char*)d_ws;
  unsigned short* xb  = (unsigned short*)ws;                          // B*D*2
  unsigned short* BTb = (unsigned short*)(ws + (size_t)B * D * 2);    // Npad*D*2
  float* rnw = (float*)(ws + (size_t)B * D * 2 + (size_t)Npad * D * 2);

  const int nxb = B / 4;           // 1024 xnorm blocks
  const int nwx = Npad / 32;       // 192 wtrans tiles per d-stripe
  const int nwb = nwx * (D / 32);  // 3072 wtrans blocks

  wnorm_kernel<<<D, 256, 0, stream>>>(W, rnw, N);
  prep_kernel<<<nxb + nwb, 256, 0, stream>>>(x, W, rnw, xb, BTb, N, nxb, nwx);
  gemm_kernel<<<(B / 128) * (Npad / 384), 512, 0, stream>>>(xb, BTb, out, N);
}

// Round 8
// 60.332 us; speedup vs baseline: 1.0611x; 1.0018x over previous
//
#include <hip/hip_runtime.h>
#include <hip/hip_bf16.h>

typedef __attribute__((ext_vector_type(8))) short short8;
typedef __attribute__((ext_vector_type(4))) float floatx4;

#define L2EPS 1e-12f

__device__ __forceinline__ unsigned short f2bf(float f) {
  union { float f; unsigned u; } c; c.f = f;
  unsigned u = c.u;
  unsigned r = (u + 0x7fffu + ((u >> 16) & 1u)) >> 16;  // RNE
  return (unsigned short)r;
}

__device__ __forceinline__ void gload_lds16(const void* g, void* l) {
  __builtin_amdgcn_global_load_lds(
      (const __attribute__((address_space(1))) unsigned int*)g,
      (__attribute__((address_space(3))) unsigned int*)l,
      16, 0, 0);
}

// ---------------------------------------------------------------------------
// Kernel 1: per-row inverse L2 norm of W (D rows of length N). One block/row.
// ---------------------------------------------------------------------------
__global__ __launch_bounds__(256) void wnorm_kernel(const float* __restrict__ W,
                                                    float* __restrict__ rnw, int N) {
  const int d = blockIdx.x;
  const float2* row2 = (const float2*)(W + (size_t)d * N);
  const int n2 = N >> 1;
  float s = 0.f;
  for (int i = threadIdx.x; i < n2; i += 256) {
    const float2 v = row2[i];
    s += v.x * v.x + v.y * v.y;
  }
  if (threadIdx.x == 0 && (N & 1)) {
    const float v = W[(size_t)d * N + (N - 1)];
    s += v * v;
  }
#pragma unroll
  for (int off = 32; off > 0; off >>= 1) s += __shfl_xor(s, off);
  __shared__ float red[4];
  if ((threadIdx.x & 63) == 0) red[threadIdx.x >> 6] = s;
  __syncthreads();
  if (threadIdx.x == 0) {
    const float t = red[0] + red[1] + red[2] + red[3];
    rnw[d] = rsqrtf(fmaxf(t, L2EPS));
  }
}

// ---------------------------------------------------------------------------
// Kernel 2 (fused dispatch): blocks [0,nxb): normalize x rows AND fold rnw.
// Blocks [nxb,...): transpose-cast BT[n][d] = bf16(W[d][n]), zero-padded.
// ---------------------------------------------------------------------------
__global__ __launch_bounds__(256) void prep_kernel(const float* __restrict__ x,
                                                   const float* __restrict__ W,
                                                   const float* __restrict__ rnw,
                                                   unsigned short* __restrict__ xb,
                                                   unsigned short* __restrict__ BT,
                                                   int N, int nxb, int nwx) {
  const int bid = blockIdx.x;
  if (bid < nxb) {
    const int lane = threadIdx.x & 63;
    const int wave = threadIdx.x >> 6;
    const int row  = bid * 4 + wave;
    const float4* xr = (const float4*)(x + (size_t)row * 512);
    const float4 v0 = xr[lane * 2];
    const float4 v1 = xr[lane * 2 + 1];
    float s = v0.x*v0.x + v0.y*v0.y + v0.z*v0.z + v0.w*v0.w
            + v1.x*v1.x + v1.y*v1.y + v1.z*v1.z + v1.w*v1.w;
#pragma unroll
    for (int off = 32; off > 0; off >>= 1) s += __shfl_xor(s, off);
    const float r = rsqrtf(fmaxf(s, L2EPS));
    const float4 w0 = ((const float4*)rnw)[lane * 2];
    const float4 w1 = ((const float4*)rnw)[lane * 2 + 1];
    short8 o;
    o[0] = (short)f2bf(v0.x * r * w0.x); o[1] = (short)f2bf(v0.y * r * w0.y);
    o[2] = (short)f2bf(v0.z * r * w0.z); o[3] = (short)f2bf(v0.w * r * w0.w);
    o[4] = (short)f2bf(v1.x * r * w1.x); o[5] = (short)f2bf(v1.y * r * w1.y);
    o[6] = (short)f2bf(v1.z * r * w1.z); o[7] = (short)f2bf(v1.w * r * w1.w);
    *(short8*)(xb + (size_t)row * 512 + lane * 8) = o;
  } else {
    __shared__ unsigned short tile[32][33];
    const int wb = bid - nxb;
    const int n0 = (wb % nwx) * 32;
    const int d0 = (wb / nwx) * 32;
    const int tx = threadIdx.x & 31;
    const int ty = threadIdx.x >> 5;  // 0..7
#pragma unroll
    for (int i = 0; i < 4; ++i) {
      const int dl = ty + i * 8;
      const int n = n0 + tx;
      float v = 0.f;
      if (n < N) v = W[(size_t)(d0 + dl) * N + n];
      tile[tx][dl] = f2bf(v);
    }
    __syncthreads();
#pragma unroll
    for (int i = 0; i < 4; ++i) {
      const int nl = ty + i * 8;
      BT[(size_t)(n0 + nl) * 512 + d0 + tx] = tile[nl][tx];
    }
  }
}

// ---------------------------------------------------------------------------
// Kernel 3: GEMM, m97-mode: 128x128 tile, 4 waves (2x2), BK=64, SINGLE LDS
// buffer (32KB -> up to 4-5 blocks/CU), two __syncthreads per K-tile,
// NO inline asm / fences / setprio -- compiler owns the schedule (m141
// lesson). Chunk-XOR swizzle (0 conflicts, r3-verified family) applied
// via pre-swizzled global SOURCE + swizzled ds_read (rule #21).
// K = 512 -> 8 K-tiles.
// ---------------------------------------------------------------------------
__global__ __launch_bounds__(256, 4) void gemm_kernel(
    const unsigned short* __restrict__ A,   // (4096,512) bf16 (xn * rnw)
    const unsigned short* __restrict__ BT,  // (6016,512) bf16 (W^T)
    float* __restrict__ C,                  // (4096,N) f32
    int N, int nbx, int nby) {
  __shared__ unsigned short As[128 * 64];
  __shared__ unsigned short Bs[128 * 64];

  const int tid = threadIdx.x;
  const int l   = tid & 63;
  const int w   = tid >> 6;   // 0..3
  const int wr  = w >> 1;     // 0..1
  const int wc  = w & 1;      // 0..1

  // XCD swizzle: 1504 = 8 x 188; column-major chunks (B-panel L2 reuse).
  const int grid = nbx * nby;
  const int bid  = blockIdx.x;
  int swz = bid;
  if ((grid & 7) == 0) swz = (bid & 7) * (grid >> 3) + (bid >> 3);
  const int bx = swz / nby;
  const int by = swz % nby;
  const int row0 = by * 128;
  const int col0 = bx * 128;

  floatx4 acc[4][4];
#pragma unroll
  for (int m = 0; m < 4; ++m)
#pragma unroll
    for (int n = 0; n < 4; ++n)
      acc[m][n] = (floatx4){0.f, 0.f, 0.f, 0.f};

  // staging: one instr = 256 thr x 16B = 4KB = 32 rows of 128B; 4 instrs per
  // matrix. LDS dest linear (tid*16B); SOURCE chunk pre-swizzled:
  // chunk_g = (tid&7) ^ (row&7), row&7 = (tid>>3)&7 (rows step by 32).
  const int srow = tid >> 3;                               // 0..31
  const int sch  = ((tid & 7) ^ (srow & 7)) * 8;           // elems
  const unsigned short* Ap = A  + (size_t)(row0 + srow) * 512 + sch;
  const unsigned short* Bp = BT + (size_t)(col0 + srow) * 512 + sch;
  const int lo = tid * 8;                                  // LDS elems

  // frag-read geometry: elem = row*64 + ((ks*4+q4)^(row&7))*8; 2 lanes/bank
  // group = conflict-free (same family measured 0 in r3).
  const int ln15 = l & 15;
  const int q4   = l >> 4;
  const int e7   = ln15 & 7;
  const int cs0  = ((q4) ^ e7) * 8;
  const int cs1  = ((4 + q4) ^ e7) * 8;
  const int aoff = (wr * 64 + ln15) * 64;   // + m*1024
  const int boff = (wc * 64 + ln15) * 64;   // + n*1024

  for (int t = 0; t < 8; ++t) {
#pragma unroll
    for (int i = 0; i < 4; ++i)
      gload_lds16(Ap + (size_t)(i * 32) * 512 + t * 64, &As[i * 2048 + lo]);
#pragma unroll
    for (int i = 0; i < 4; ++i)
      gload_lds16(Bp + (size_t)(i * 32) * 512 + t * 64, &Bs[i * 2048 + lo]);
    __syncthreads();
#pragma unroll
    for (int ks = 0; ks < 2; ++ks) {
      const int cs = ks ? cs1 : cs0;
      short8 af[4], bf[4];
#pragma unroll
      for (int m = 0; m < 4; ++m) af[m] = *(const short8*)&As[aoff + m * 1024 + cs];
#pragma unroll
      for (int n = 0; n < 4; ++n) bf[n] = *(const short8*)&Bs[boff + n * 1024 + cs];
#pragma unroll
      for (int m = 0; m < 4; ++m)
#pragma unroll
        for (int n = 0; n < 4; ++n)
          acc[m][n] = __builtin_amdgcn_mfma_f32_16x16x32_bf16(af[m], bf[n], acc[m][n], 0, 0, 0);
    }
    __syncthreads();
  }

  // epilogue: C/D layout col=lane&15, row=(lane>>4)*4+r; n-inner
  const int rb = row0 + wr * 64 + q4 * 4;
  const int cb = col0 + wc * 64 + ln15;
#pragma unroll
  for (int m = 0; m < 4; ++m) {
#pragma unroll
    for (int r = 0; r < 4; ++r) {
      const size_t o = (size_t)(rb + m * 16 + r) * N + cb;
#pragma unroll
      for (int n = 0; n < 4; ++n) {
        if (cb + n * 16 < N) C[o + n * 16] = acc[m][n][r];
      }
    }
  }
}

// ---------------------------------------------------------------------------
extern "C" void kernel_launch(void* const* d_in, const int* in_sizes, int n_in,
                              void* d_out, int out_size, void* d_ws, size_t ws_size,
                              hipStream_t stream) {
  const float* x = (const float*)d_in[0];
  const float* W = (const float*)d_in[1];
  float* out = (float*)d_out;

  const int D = 512;
  const int B = in_sizes[0] / D;            // 4096
  const int N = in_sizes[1] / D;            // 5994
  const int Npad = ((N + 127) / 128) * 128; // 6016

  char* ws = (char*)d_ws;
  unsigned short* xb  = (unsigned short*)ws;                          // B*D*2
  unsigned short* BTb = (unsigned short*)(ws + (size_t)B * D * 2);    // Npad*D*2
  float* rnw = (float*)(ws + (size_t)B * D * 2 + (size_t)Npad * D * 2);

  const int nby = B / 128;         // 32
  const int nbx = Npad / 128;      // 47
  const int nxb = B / 4;           // 1024 xnorm blocks
  const int nwx = Npad / 32;       // 188 wtrans tiles per d-stripe
  const int nwb = nwx * (D / 32);  // 3008 wtrans blocks

  wnorm_kernel<<<D, 256, 0, stream>>>(W, rnw, N);
  prep_kernel<<<nxb + nwb, 256, 0, stream>>>(x, W, rnw, xb, BTb, N, nxb, nwx);
  gemm_kernel<<<nbx * nby, 256, 0, stream>>>(xb, BTb, out, N, nbx, nby);
}